// Round 4
// baseline (564.003 us; speedup 1.0000x reference)
//
#include <hip/hip_runtime.h>
#include <cstdint>
#include <cstddef>

typedef __bf16 bf16;
typedef __bf16 bf16x8 __attribute__((ext_vector_type(8)));
typedef float  f32x4  __attribute__((ext_vector_type(4)));
typedef unsigned short u16;
typedef u16 u16x8 __attribute__((ext_vector_type(8)));

static_assert(sizeof(bf16x8) == 16, "bf16x8 must be 16B");

// async global->LDS, 16B per lane. LDS dest is wave-uniform base; HW deposits
// lane i's 16B at ldsbase + i*16.
__device__ __forceinline__ void async_copy16(const bf16* g, bf16* l) {
  __builtin_amdgcn_global_load_lds(
      (__attribute__((address_space(1))) void*)(g),
      (__attribute__((address_space(3))) void*)(l),
      16, 0, 0);
}

// Input-dtype probe: read the first 2048 16-bit halves of x (block-uniform
// result). True bf16 N(0,1) data: every exponent field <= 129 (|v| < 8).
// fp32 data: ~1024 of these halves are fp32 mantissa garbage with ~uniform
// exponent field -> P(detect) = 1 - (137/256)^1024 ~ 1 - 1e-278.
// Call with all 256 threads; contains uniform barriers.
__device__ __forceinline__ bool detect_fp32_mode(const u16* xdet) {
  __shared__ int s_flag;
  const int tid = threadIdx.x;
  if (tid == 0) s_flag = 0;
  __syncthreads();
  const u16x8 w = ((const u16x8*)xdet)[tid];
  int bad = 0;
#pragma unroll
  for (int e = 0; e < 8; ++e) bad |= (((w[e] >> 7) & 0xFF) >= 137) ? 1 : 0;
  if (bad) s_flag = 1;
  __syncthreads();
  return s_flag != 0;
}

// C[m,n] = sum_k A[m,k] * W[n,k].  W:[N,K] row-major (torch Linear layout).
// Tile 128x128, BK=64, 4 waves (2x2), each wave 64x64 = 4x4 MFMA 16x16x32 tiles.
// LDS layout: [row][chunk], chunk = 16B of 8 bf16 along K, XOR swizzle
// chunk_lds = chunk_glb ^ (row&7). Invariant: LDS[row][c] = G[row][c^(row&7)],
// maintained identically by the async path (lane deposit rule) and the manual
// fp32 path; fragment reads apply the same XOR.
// MODE 1: A = x (fp32 or bf16 per flag); C scattered bf16 into per-plane
//         [b][h][s][d] bases: n<2048 -> Cq, n<4096 -> Ck, else Cv.
// MODE 2: A gathered bf16 from a [b][h][s][d] plane (k = h*128+d);
//         C row-major -> Cq as fp32 or bf16 per flag.
// W is fp32 or bf16 per flag in both modes.
template<int MODE>
__global__ __launch_bounds__(256, 2)
void gemm_bt_kernel(const void* __restrict__ A_, const void* __restrict__ W_,
                    void* __restrict__ Cq, bf16* __restrict__ Ck,
                    bf16* __restrict__ Cv, const u16* __restrict__ xdet,
                    int M, int N, int K) {
  __shared__ bf16 As[128 * 64];
  __shared__ bf16 Ws[128 * 64];

  const bool fp32mode = detect_fp32_mode(xdet);

  const int tid  = threadIdx.x;
  const int wave = tid >> 6;
  const int lane = tid & 63;
  const int quad = lane >> 4;
  const int r    = lane & 15;
  const int m0 = blockIdx.y * 128;
  const int n0 = blockIdx.x * 128;
  const int wm = (wave >> 1) * 64;
  const int wn = (wave & 1) * 64;

  const int lrow   = lane >> 3;      // 0..7 row within an 8-row async issue
  const int lchunk = lane & 7;       // LDS chunk slot
  const int gchunk = lchunk ^ lrow;  // swizzled global chunk

  f32x4 acc[4][4] = {};

  for (int k0 = 0; k0 < K; k0 += 64) {
    __syncthreads();
    // ---- A staging ----
    if (MODE == 2 || !fp32mode) {
      for (int j = 0; j < 4; ++j) {
        const int rbase = (wave * 4 + j) * 8;
        const int rowA  = m0 + rbase + lrow;
        const bf16* aSrc;
        if constexpr (MODE == 2) {
          const int b = rowA >> 11, s = rowA & 2047;
          aSrc = (const bf16*)A_ + ((size_t)(b * 16 + (k0 >> 7)) * 2048 + s) * 128
                   + (k0 & 127) + gchunk * 8;
        } else {
          aSrc = (const bf16*)A_ + (size_t)rowA * K + k0 + gchunk * 8;
        }
        async_copy16(aSrc, As + rbase * 64);
      }
    } else {
      const float* Afp = (const float*)A_;
      for (int j = 0; j < 4; ++j) {
        const int lin = j * 256 + tid;
        const int row = lin >> 3, c = lin & 7;
        const int gc  = c ^ (row & 7);
        const float* src = Afp + (size_t)(m0 + row) * K + k0 + gc * 8;
        bf16x8 v;
#pragma unroll
        for (int e = 0; e < 8; ++e) v[e] = (bf16)src[e];
        *(bf16x8*)(As + row * 64 + c * 8) = v;
      }
    }
    // ---- W staging ----
    if (!fp32mode) {
      for (int j = 0; j < 4; ++j) {
        const int rbase = (wave * 4 + j) * 8;
        async_copy16((const bf16*)W_ + (size_t)(n0 + rbase + lrow) * K + k0 + gchunk * 8,
                     Ws + rbase * 64);
      }
    } else {
      const float* Wfp = (const float*)W_;
      for (int j = 0; j < 4; ++j) {
        const int lin = j * 256 + tid;
        const int row = lin >> 3, c = lin & 7;
        const int gc  = c ^ (row & 7);
        const float* src = Wfp + (size_t)(n0 + row) * K + k0 + gc * 8;
        bf16x8 v;
#pragma unroll
        for (int e = 0; e < 8; ++e) v[e] = (bf16)src[e];
        *(bf16x8*)(Ws + row * 64 + c * 8) = v;
      }
    }
    __syncthreads();
    for (int ks = 0; ks < 2; ++ks) {
      bf16x8 af[4], bfv[4];
      for (int i = 0; i < 4; ++i) {
        const int ar = wm + i * 16 + r;
        af[i]  = *(const bf16x8*)(As + ar * 64 + (((ks * 4 + quad) ^ (ar & 7)) * 8));
        const int br = wn + i * 16 + r;
        bfv[i] = *(const bf16x8*)(Ws + br * 64 + (((ks * 4 + quad) ^ (br & 7)) * 8));
      }
      for (int i = 0; i < 4; ++i)
        for (int j = 0; j < 4; ++j)
          acc[i][j] = __builtin_amdgcn_mfma_f32_16x16x32_bf16(af[i], bfv[j], acc[i][j], 0, 0, 0);
    }
  }

  // C-layout: row = quad*4+reg, col = lane&15 (m89-verified).
  for (int i = 0; i < 4; ++i) {
    const int growb = m0 + wm + i * 16 + quad * 4;
    for (int j = 0; j < 4; ++j) {
      const int gcol = n0 + wn + j * 16 + r;
      for (int rg = 0; rg < 4; ++rg) {
        const int grow = growb + rg;
        if constexpr (MODE == 1) {
          const int which = gcol >> 11;
          bf16* base = (which == 0) ? (bf16*)Cq : ((which == 1) ? Ck : Cv);
          const int h = (gcol >> 7) & 15;
          const int d = gcol & 127;
          const int b = grow >> 11;
          const int s = grow & 2047;
          base[(((size_t)b * 16 + h) * 2048 + s) * 128 + d] = (bf16)acc[i][j][rg];
        } else {
          if (fp32mode)
            ((float*)Cq)[(size_t)grow * N + gcol] = acc[i][j][rg];
          else
            ((bf16*)Cq)[(size_t)grow * N + gcol] = (bf16)acc[i][j][rg];
        }
      }
    }
  }
}

// Flash attention, causal. Q,K,V: [B*H, S, 128] bf16 planes (always bf16 —
// they are our own workspace). Output written IN-PLACE into the Q plane:
// block (bh,qb) reads only its own Q rows (into registers, at kernel start)
// and is the only block writing those rows -> race-free.
// Grid: (S/128, B*H), block 256. Wave w owns q rows q0+w*32..+32.
__global__ __launch_bounds__(256, 2)
void attn_kernel(bf16* __restrict__ Q, const bf16* __restrict__ K,
                 const bf16* __restrict__ V, int S) {
  __shared__ bf16 k_lds[64 * 136];   // [kv][d], pad 136 for bank balance
  __shared__ bf16 v_lds[128 * 72];   // transposed: [d][kv], pad 72
  __shared__ bf16 p_lds[4][32 * 72]; // per-wave P scratch [qrow][kv]

  const int tid = threadIdx.x, wave = tid >> 6, lane = tid & 63;
  const int quad = lane >> 4, r = lane & 15;
  const int bh = blockIdx.y;
  const int q0 = blockIdx.x * 128;
  const int qrow0 = q0 + wave * 32;
  bf16* Qh = Q + (size_t)bh * S * 128;
  const bf16* Kh = K + (size_t)bh * S * 128;
  const bf16* Vh = V + (size_t)bh * S * 128;

  // Q fragments resident in registers: A[m=lane&15][k=quad*8+j] per 32-k step
  bf16x8 qf[2][4];
  for (int mt = 0; mt < 2; ++mt)
    for (int ks = 0; ks < 4; ++ks)
      qf[mt][ks] = *(const bf16x8*)(Qh + (size_t)(qrow0 + mt * 16 + r) * 128 + ks * 32 + quad * 8);

  f32x4 o_acc[2][8] = {};
  f32x4 m_run[2], l_run[2];
  for (int mt = 0; mt < 2; ++mt)
    for (int t = 0; t < 4; ++t) { m_run[mt][t] = -1e30f; l_run[mt][t] = 0.f; }

  const float sc = 0.0883883476483184f * 1.4426950408889634f; // 1/sqrt(128) * log2(e)
  const int vch = tid >> 4;  // d-chunk 0..15 for V transpose staging
  const int vr  = tid & 15;
  const int nkv = (q0 + 128) >> 6;

  for (int kt = 0; kt < nkv; ++kt) {
    const int kv0 = kt << 6;
    __syncthreads();
    // stage K row-major [64][128] with pad
    for (int j = 0; j < 4; ++j) {
      const int lin = j * 256 + tid;
      const int row = lin >> 4;
      const int ch  = lin & 15;
      *(bf16x8*)(k_lds + row * 136 + ch * 8) =
          *(const bf16x8*)(Kh + (size_t)(kv0 + row) * 128 + ch * 8);
    }
    // stage V transposed [128 d][64 kv]
    for (int j = 0; j < 4; ++j) {
      const int row = vr + j * 16;
      const bf16x8 vv = *(const bf16x8*)(Vh + (size_t)(kv0 + row) * 128 + vch * 8);
      for (int e = 0; e < 8; ++e) v_lds[(vch * 8 + e) * 72 + row] = vv[e];
    }
    __syncthreads();

    if (kv0 <= qrow0 + 31) {  // tile not fully masked for this wave
      // S = Q K^T
      f32x4 sa[2][4] = {};
      for (int ks = 0; ks < 4; ++ks) {
        bf16x8 kf[4];
        for (int nt = 0; nt < 4; ++nt)
          kf[nt] = *(const bf16x8*)(k_lds + (nt * 16 + r) * 136 + ks * 32 + quad * 8);
        for (int mt = 0; mt < 2; ++mt)
          for (int nt = 0; nt < 4; ++nt)
            sa[mt][nt] = __builtin_amdgcn_mfma_f32_16x16x32_bf16(qf[mt][ks], kf[nt], sa[mt][nt], 0, 0, 0);
      }
      // causal mask on diagonal tiles
      if (kv0 + 63 > qrow0) {
        for (int mt = 0; mt < 2; ++mt)
          for (int nt = 0; nt < 4; ++nt) {
            const int col  = kv0 + nt * 16 + r;
            const int rowb = qrow0 + mt * 16 + quad * 4;
            for (int rg = 0; rg < 4; ++rg)
              if (col > rowb + rg) sa[mt][nt][rg] = -1e30f;
          }
      }
      // online softmax (each S row lives on the 16 lanes of one quad group)
      for (int mt = 0; mt < 2; ++mt) {
        f32x4 mx = sa[mt][0];
        for (int nt = 1; nt < 4; ++nt)
          for (int rg = 0; rg < 4; ++rg) mx[rg] = fmaxf(mx[rg], sa[mt][nt][rg]);
        for (int off = 1; off < 16; off <<= 1)
          for (int rg = 0; rg < 4; ++rg) mx[rg] = fmaxf(mx[rg], __shfl_xor(mx[rg], off, 64));
        f32x4 alpha;
        for (int rg = 0; rg < 4; ++rg) {
          const float mnew = fmaxf(m_run[mt][rg], mx[rg]);
          alpha[rg] = exp2f((m_run[mt][rg] - mnew) * sc);
          m_run[mt][rg] = mnew;
        }
        f32x4 rsum = {0.f, 0.f, 0.f, 0.f};
        for (int nt = 0; nt < 4; ++nt)
          for (int rg = 0; rg < 4; ++rg) {
            const float p = exp2f((sa[mt][nt][rg] - m_run[mt][rg]) * sc);
            sa[mt][nt][rg] = p;
            rsum[rg] += p;
          }
        for (int off = 1; off < 16; off <<= 1)
          for (int rg = 0; rg < 4; ++rg) rsum[rg] += __shfl_xor(rsum[rg], off, 64);
        for (int rg = 0; rg < 4; ++rg) l_run[mt][rg] = l_run[mt][rg] * alpha[rg] + rsum[rg];
        for (int nt2 = 0; nt2 < 8; ++nt2)
          for (int rg = 0; rg < 4; ++rg) o_acc[mt][nt2][rg] *= alpha[rg];
        // P: C-layout -> A-layout via per-wave LDS round-trip (m120 pattern)
        for (int nt = 0; nt < 4; ++nt)
          for (int rg = 0; rg < 4; ++rg)
            p_lds[wave][(mt * 16 + quad * 4 + rg) * 72 + nt * 16 + r] = (bf16)sa[mt][nt][rg];
      }
      // O += P V
      for (int ks2 = 0; ks2 < 2; ++ks2) {
        bf16x8 pf[2];
        for (int mt = 0; mt < 2; ++mt)
          pf[mt] = *(const bf16x8*)(p_lds[wave] + (mt * 16 + r) * 72 + ks2 * 32 + quad * 8);
        for (int nt2 = 0; nt2 < 8; ++nt2) {
          const bf16x8 vf = *(const bf16x8*)(v_lds + (nt2 * 16 + r) * 72 + ks2 * 32 + quad * 8);
          for (int mt = 0; mt < 2; ++mt)
            o_acc[mt][nt2] = __builtin_amdgcn_mfma_f32_16x16x32_bf16(pf[mt], vf, o_acc[mt][nt2], 0, 0, 0);
        }
      }
    }
  }

  // epilogue: write O back into the Q plane, same [b,h,s,d] coords
  for (int mt = 0; mt < 2; ++mt) {
    f32x4 inv;
    for (int rg = 0; rg < 4; ++rg) inv[rg] = 1.0f / l_run[mt][rg];
    for (int nt2 = 0; nt2 < 8; ++nt2) {
      const int d = nt2 * 16 + r;
      for (int rg = 0; rg < 4; ++rg) {
        const int s = qrow0 + mt * 16 + quad * 4 + rg;
        Qh[(size_t)s * 128 + d] = (bf16)(o_acc[mt][nt2][rg] * inv[rg]);
      }
    }
  }
}

extern "C" void kernel_launch(void* const* d_in, const int* in_sizes, int n_in,
                              void* d_out, int out_size, void* d_ws, size_t ws_size,
                              hipStream_t stream) {
  const void* x     = d_in[0];   // [2,2048,2048], fp32 or bf16 (auto-detected)
  const void* Wqkv  = d_in[1];   // [6144,2048]
  const void* Wproj = d_in[2];   // [2048,2048]
  const u16* xdet = (const u16*)d_in[0];

  const int Bm = 4096;  // B*S
  const int E  = 2048;
  const size_t plane = 8388608;  // B*H*S*D elems = 16 MiB bf16

  // Memory plan (ws footprint = 32 MiB):
  //   ws[0..plane)        : Q plane [B,H,S,D] bf16; attention writes O in-place
  //   ws[plane..2*plane)  : V plane [B,H,S,D] bf16
  //   d_out               : K plane bf16 (fits: out is >= 16 MiB in either
  //                         dtype), dead after attention; proj then overwrites.
  bf16* qw = (bf16*)d_ws;
  bf16* vw = qw + plane;
  bf16* kw = (bf16*)d_out;

  gemm_bt_kernel<1><<<dim3(6144 / 128, Bm / 128), 256, 0, stream>>>(
      x, Wqkv, qw, kw, vw, xdet, Bm, 6144, E);
  attn_kernel<<<dim3(2048 / 128, 32), 256, 0, stream>>>(qw, kw, vw, 2048);
  gemm_bt_kernel<2><<<dim3(2048 / 128, Bm / 128), 256, 0, stream>>>(
      qw, Wproj, d_out, nullptr, nullptr, xdet, Bm, 2048, E);
}

// Round 5
// 443.203 us; speedup vs baseline: 1.2726x; 1.2726x over previous
//
#include <hip/hip_runtime.h>
#include <cstdint>
#include <cstddef>

typedef __bf16 bf16;
typedef __bf16 bf16x8 __attribute__((ext_vector_type(8)));
typedef float  f32x4  __attribute__((ext_vector_type(4)));

static_assert(sizeof(bf16x8) == 16, "bf16x8 must be 16B");

// async global->LDS, 16B per lane; lane i's data lands at ldsbase + i*16.
__device__ __forceinline__ void async_copy16(const bf16* g, bf16* l) {
  __builtin_amdgcn_global_load_lds(
      (__attribute__((address_space(1))) void*)(g),
      (__attribute__((address_space(3))) void*)(l),
      16, 0, 0);
}

// fp32 -> bf16 bulk convert, 8 elems/thread. n must be a multiple of 2048.
__global__ __launch_bounds__(256)
void conv_f32_bf16(const float* __restrict__ s, bf16* __restrict__ d) {
  const size_t i = ((size_t)blockIdx.x * 256 + threadIdx.x) * 8;
  const f32x4 a = *(const f32x4*)(s + i);
  const f32x4 b = *(const f32x4*)(s + i + 4);
  bf16x8 o;
#pragma unroll
  for (int e = 0; e < 4; ++e) { o[e] = (bf16)a[e]; o[4 + e] = (bf16)b[e]; }
  *(bf16x8*)(d + i) = o;
}

// C[m,n] = sum_k A[m,k] * W[n,k], all-bf16 m97-style: 128x128 tile, BK=64,
// async global->LDS both operands, XOR chunk swizzle (LDS[row][c]=G[row][c^(row&7)]).
// AMODE 0: A row-major [M,K].  AMODE 2: A gathered from [B,H,S,D] plane (k=h*128+d).
// CMODE 0: C fp32 row-major -> Crow.
// CMODE 1: C scattered bf16; global col = nbase+n: <2048 -> Cq[b,h,s,d],
//          <4096 -> Ck[b,h,s,d], else -> Cvt TRANSPOSED [b,h,d,s].
template<int AMODE, int CMODE>
__global__ __launch_bounds__(256, 2)
void gemm_bt(const bf16* __restrict__ A, const bf16* __restrict__ W,
             float* __restrict__ Crow, bf16* __restrict__ Cq,
             bf16* __restrict__ Ck, bf16* __restrict__ Cvt,
             int M, int N, int K, int nbase) {
  __shared__ bf16 As[128 * 64];
  __shared__ bf16 Ws[128 * 64];

  const int tid  = threadIdx.x;
  const int wave = tid >> 6;
  const int lane = tid & 63;
  const int quad = lane >> 4;
  const int r    = lane & 15;
  const int m0 = blockIdx.y * 128;
  const int n0 = blockIdx.x * 128;
  const int wm = (wave >> 1) * 64;
  const int wn = (wave & 1) * 64;

  const int lrow   = lane >> 3;      // 0..7
  const int gchunk = (lane & 7) ^ lrow;

  f32x4 acc[4][4] = {};

  for (int k0 = 0; k0 < K; k0 += 64) {
    __syncthreads();
    for (int j = 0; j < 4; ++j) {
      const int rbase = (wave * 4 + j) * 8;
      const int rowA  = m0 + rbase + lrow;
      const bf16* aSrc;
      if constexpr (AMODE == 2) {
        const int b = rowA >> 11, s = rowA & 2047;
        aSrc = A + ((size_t)(b * 16 + (k0 >> 7)) * 2048 + s) * 128
                 + (k0 & 127) + gchunk * 8;
      } else {
        aSrc = A + (size_t)rowA * K + k0 + gchunk * 8;
      }
      async_copy16(aSrc, As + rbase * 64);
      async_copy16(W + (size_t)(n0 + rbase + lrow) * K + k0 + gchunk * 8,
                   Ws + rbase * 64);
    }
    __syncthreads();
    for (int ks = 0; ks < 2; ++ks) {
      bf16x8 af[4], bfv[4];
      for (int i = 0; i < 4; ++i) {
        const int ar = wm + i * 16 + r;
        af[i]  = *(const bf16x8*)(As + ar * 64 + (((ks * 4 + quad) ^ (ar & 7)) * 8));
        const int br = wn + i * 16 + r;
        bfv[i] = *(const bf16x8*)(Ws + br * 64 + (((ks * 4 + quad) ^ (br & 7)) * 8));
      }
      for (int i = 0; i < 4; ++i)
        for (int j = 0; j < 4; ++j)
          acc[i][j] = __builtin_amdgcn_mfma_f32_16x16x32_bf16(af[i], bfv[j], acc[i][j], 0, 0, 0);
    }
  }

  // C-layout: row = quad*4+reg, col = lane&15 (m89-verified).
  for (int i = 0; i < 4; ++i) {
    const int growb = m0 + wm + i * 16 + quad * 4;
    for (int j = 0; j < 4; ++j) {
      const int gcol = n0 + wn + j * 16 + r;
      for (int rg = 0; rg < 4; ++rg) {
        const int grow = growb + rg;
        if constexpr (CMODE == 1) {
          const int gc = nbase + gcol;
          const int which = gc >> 11;
          const int h = (gc >> 7) & 15;
          const int d = gc & 127;
          const int b = grow >> 11;
          const int s = grow & 2047;
          const bf16 v = (bf16)acc[i][j][rg];
          if (which == 0)
            Cq[(((size_t)b * 16 + h) * 2048 + s) * 128 + d] = v;
          else if (which == 1)
            Ck[(((size_t)b * 16 + h) * 2048 + s) * 128 + d] = v;
          else
            Cvt[(((size_t)b * 16 + h) * 128 + d) * 2048 + s] = v;  // transposed
        } else {
          Crow[(size_t)grow * N + gcol] = acc[i][j][rg];
        }
      }
    }
  }
}

// Flash attention, causal. Q,K: [B*H, S, 128] bf16; Vt: [B*H, 128, S] bf16
// (pre-transposed). O written IN-PLACE into the Q plane (block-private rows).
// Grid: (S/128, B*H); qb REVERSED so heavy diagonal blocks dispatch first.
// All LDS XOR-swizzled on 8-elem chunks: LDS[row][c] holds G[row][c^(row&7)].
__global__ __launch_bounds__(256, 2)
void attn_kernel(bf16* __restrict__ Q, const bf16* __restrict__ K,
                 const bf16* __restrict__ Vt, int S) {
  __shared__ bf16 k_lds[64 * 128];   // [kv][d], swizzled
  __shared__ bf16 v_lds[128 * 64];   // [d][kv], swizzled
  __shared__ bf16 p_lds[4][32 * 64]; // per-wave P [qrow][kv], swizzled

  const int tid = threadIdx.x, wave = tid >> 6, lane = tid & 63;
  const int quad = lane >> 4, r = lane & 15;
  const int bh = blockIdx.y;
  const int q0 = (gridDim.x - 1 - blockIdx.x) * 128;  // reversed for balance
  const int qrow0 = q0 + wave * 32;
  bf16* Qh = Q + (size_t)bh * S * 128;
  const bf16* Kh = K + (size_t)bh * S * 128;
  const bf16* Vth = Vt + (size_t)bh * 128 * S;

  // Q fragments in registers: A[m=lane&15][k=quad*8+j] per 32-k step
  bf16x8 qf[2][4];
  for (int mt = 0; mt < 2; ++mt)
    for (int ks = 0; ks < 4; ++ks)
      qf[mt][ks] = *(const bf16x8*)(Qh + (size_t)(qrow0 + mt * 16 + r) * 128 + ks * 32 + quad * 8);

  f32x4 o_acc[2][8] = {};
  f32x4 m_run[2], l_run[2];
  for (int mt = 0; mt < 2; ++mt)
    for (int t = 0; t < 4; ++t) { m_run[mt][t] = -1e30f; l_run[mt][t] = 0.f; }

  const float sc = 0.0883883476483184f * 1.4426950408889634f; // 1/sqrt(128)*log2e
  const int nkv = (q0 + 128) >> 6;

  for (int kt = 0; kt < nkv; ++kt) {
    const int kv0 = kt << 6;
    __syncthreads();
    // stage K [64 kv][16 chunks of 8 d], swizzled
    for (int j = 0; j < 4; ++j) {
      const int lin = j * 256 + tid;
      const int row = lin >> 4;
      const int ch  = lin & 15;
      *(bf16x8*)(k_lds + row * 128 + (ch ^ (row & 7)) * 8) =
          *(const bf16x8*)(Kh + (size_t)(kv0 + row) * 128 + ch * 8);
    }
    // stage V^T [128 d][8 chunks of 8 kv], swizzled — vectorized both sides
    for (int j = 0; j < 4; ++j) {
      const int lin = j * 256 + tid;
      const int row = lin >> 3;   // d
      const int c   = lin & 7;    // kv chunk
      *(bf16x8*)(v_lds + row * 64 + (c ^ (row & 7)) * 8) =
          *(const bf16x8*)(Vth + (size_t)row * S + kv0 + c * 8);
    }
    __syncthreads();

    if (kv0 <= qrow0 + 31) {  // tile not fully masked for this wave
      // S = Q K^T
      f32x4 sa[2][4] = {};
      for (int ks = 0; ks < 4; ++ks) {
        bf16x8 kf[4];
        for (int nt = 0; nt < 4; ++nt) {
          const int kr = nt * 16 + r;
          kf[nt] = *(const bf16x8*)(k_lds + kr * 128 + (((ks * 4 + quad) ^ (kr & 7)) * 8));
        }
        for (int mt = 0; mt < 2; ++mt)
          for (int nt = 0; nt < 4; ++nt)
            sa[mt][nt] = __builtin_amdgcn_mfma_f32_16x16x32_bf16(qf[mt][ks], kf[nt], sa[mt][nt], 0, 0, 0);
      }
      // causal mask on diagonal tiles
      if (kv0 + 63 > qrow0) {
        for (int mt = 0; mt < 2; ++mt)
          for (int nt = 0; nt < 4; ++nt) {
            const int col  = kv0 + nt * 16 + r;
            const int rowb = qrow0 + mt * 16 + quad * 4;
            for (int rg = 0; rg < 4; ++rg)
              if (col > rowb + rg) sa[mt][nt][rg] = -1e30f;
          }
      }
      // online softmax (each score row lives on the 16 lanes of one quad)
      for (int mt = 0; mt < 2; ++mt) {
        f32x4 mx = sa[mt][0];
        for (int nt = 1; nt < 4; ++nt)
          for (int rg = 0; rg < 4; ++rg) mx[rg] = fmaxf(mx[rg], sa[mt][nt][rg]);
        for (int off = 1; off < 16; off <<= 1)
          for (int rg = 0; rg < 4; ++rg) mx[rg] = fmaxf(mx[rg], __shfl_xor(mx[rg], off, 64));
        f32x4 alpha;
        for (int rg = 0; rg < 4; ++rg) {
          const float mnew = fmaxf(m_run[mt][rg], mx[rg]);
          alpha[rg] = exp2f((m_run[mt][rg] - mnew) * sc);
          m_run[mt][rg] = mnew;
        }
        f32x4 rsum = {0.f, 0.f, 0.f, 0.f};
        for (int nt = 0; nt < 4; ++nt)
          for (int rg = 0; rg < 4; ++rg) {
            const float p = exp2f((sa[mt][nt][rg] - m_run[mt][rg]) * sc);
            sa[mt][nt][rg] = p;
            rsum[rg] += p;
          }
        for (int off = 1; off < 16; off <<= 1)
          for (int rg = 0; rg < 4; ++rg) rsum[rg] += __shfl_xor(rsum[rg], off, 64);
        for (int rg = 0; rg < 4; ++rg) l_run[mt][rg] = l_run[mt][rg] * alpha[rg] + rsum[rg];
        for (int nt2 = 0; nt2 < 8; ++nt2)
          for (int rg = 0; rg < 4; ++rg) o_acc[mt][nt2][rg] *= alpha[rg];
        // P: C-layout -> A-layout via per-wave LDS round-trip, swizzled
        for (int nt = 0; nt < 4; ++nt)
          for (int rg = 0; rg < 4; ++rg) {
            const int prow = mt * 16 + quad * 4 + rg;
            const int pcol = nt * 16 + r;
            p_lds[wave][prow * 64 + (((pcol >> 3) ^ (prow & 7)) * 8) + (pcol & 7)] =
                (bf16)sa[mt][nt][rg];
          }
      }
      // O += P V
      for (int ks2 = 0; ks2 < 2; ++ks2) {
        bf16x8 pf[2];
        for (int mt = 0; mt < 2; ++mt) {
          const int prow = mt * 16 + r;
          pf[mt] = *(const bf16x8*)(p_lds[wave] + prow * 64 + (((ks2 * 4 + quad) ^ (prow & 7)) * 8));
        }
        for (int nt2 = 0; nt2 < 8; ++nt2) {
          const int vrow = nt2 * 16 + r;
          const bf16x8 vf = *(const bf16x8*)(v_lds + vrow * 64 + (((ks2 * 4 + quad) ^ (vrow & 7)) * 8));
          for (int mt = 0; mt < 2; ++mt)
            o_acc[mt][nt2] = __builtin_amdgcn_mfma_f32_16x16x32_bf16(pf[mt], vf, o_acc[mt][nt2], 0, 0, 0);
        }
      }
    }
  }

  // epilogue: write O back into the Q plane, same [b,h,s,d] coords
  for (int mt = 0; mt < 2; ++mt) {
    f32x4 inv;
    for (int rg = 0; rg < 4; ++rg) inv[rg] = 1.0f / l_run[mt][rg];
    for (int nt2 = 0; nt2 < 8; ++nt2) {
      const int d = nt2 * 16 + r;
      for (int rg = 0; rg < 4; ++rg) {
        const int s = qrow0 + mt * 16 + quad * 4 + rg;
        Qh[(size_t)s * 128 + d] = (bf16)(o_acc[mt][nt2][rg] * inv[rg]);
      }
    }
  }
}

extern "C" void kernel_launch(void* const* d_in, const int* in_sizes, int n_in,
                              void* d_out, int out_size, void* d_ws, size_t ws_size,
                              hipStream_t stream) {
  const float* x     = (const float*)d_in[0];   // [2,2048,2048] fp32
  const float* Wqkv  = (const float*)d_in[1];   // [6144,2048] fp32
  const float* Wproj = (const float*)d_in[2];   // [2048,2048] fp32
  float* out = (float*)d_out;                   // [2,2048,2048] fp32 = 32 MiB

  const int Bm = 4096, E = 2048;
  const size_t plane = 8388608;                 // 16 MiB as bf16

  // ws (48 MiB): [0,plane) Q plane; [plane,2p) V^T plane; [2p,3p) xb then Wproj_bf16.
  // d_out (32 MiB): [0,plane) bf16 K plane; [plane,+6291456) bf16 Wqkv half;
  //   both dead before proj GEMM overwrites d_out with fp32 output.
  bf16* qw  = (bf16*)d_ws;
  bf16* vtw = qw + plane;
  bf16* xb  = vtw + plane;       // later reused for Wproj bf16
  bf16* kw  = (bf16*)d_out;
  bf16* wqb = kw + plane;        // 6291456 elems = 12 MiB, fits in d_out upper half

  // 1) x -> bf16
  conv_f32_bf16<<<8388608 / 2048, 256, 0, stream>>>(x, xb);
  // 2) Wqkv rows [0,3072) -> bf16
  conv_f32_bf16<<<6291456 / 2048, 256, 0, stream>>>(Wqkv, wqb);
  // 3) QKV GEMM chunk A: n in [0,3072) -> all Q + K heads 0..7
  gemm_bt<0, 1><<<dim3(3072 / 128, Bm / 128), 256, 0, stream>>>(
      xb, wqb, nullptr, qw, kw, vtw, Bm, 3072, E, 0);
  // 4) Wqkv rows [3072,6144) -> bf16 (overwrites wqb after chunk A)
  conv_f32_bf16<<<6291456 / 2048, 256, 0, stream>>>(Wqkv + 6291456, wqb);
  // 5) QKV GEMM chunk B: n in [3072,6144) -> K heads 8..15 + all V (transposed)
  gemm_bt<0, 1><<<dim3(3072 / 128, Bm / 128), 256, 0, stream>>>(
      xb, wqb, nullptr, qw, kw, vtw, Bm, 3072, E, 3072);
  // 6) attention (O overwrites Q plane)
  attn_kernel<<<dim3(2048 / 128, 32), 256, 0, stream>>>(qw, kw, vtw, 2048);
  // 7) Wproj -> bf16 (xb region; xb dead)
  conv_f32_bf16<<<4194304 / 2048, 256, 0, stream>>>(Wproj, xb);
  // 8) proj GEMM: A = O plane (gather), C = d_out fp32
  gemm_bt<2, 0><<<dim3(2048 / 128, Bm / 128), 256, 0, stream>>>(
      qw, xb, out, nullptr, nullptr, nullptr, Bm, 2048, E, 0);
}